// Round 6
// baseline (11970.425 us; speedup 1.0000x reference)
//
#include <hip/hip_runtime.h>
#include <hip/hip_bf16.h>
#include <hip/hip_cooperative_groups.h>

namespace cg = cooperative_groups;

#define T_STEPS 512
// ws: Xf bf16 frag-major [0,32MiB) | tagged h ring 2 x 128KiB
#define RING_OFF 33554432u
#define WS_NEED  33816576u

typedef __attribute__((ext_vector_type(4))) float f32x4;
typedef __attribute__((ext_vector_type(8))) short short8;
typedef __attribute__((ext_vector_type(4))) unsigned int u32x4;

__device__ __forceinline__ short f2bf(float f) {
  __hip_bfloat16 h = __float2bfloat16(f);   // RNE
  return *reinterpret_cast<short*>(&h);
}
__device__ __forceinline__ unsigned bfbits(float f) {
  __hip_bfloat16 h = __float2bfloat16(f);
  return (unsigned)*reinterpret_cast<unsigned short*>(&h);
}
__device__ __forceinline__ short8 as_s8(u32x4 v) {
  union { u32x4 u; short8 s; } x; x.u = v; return x.s;
}

__global__ __launch_bounds__(512, 2) void lstm_kernel(
    const float* __restrict__ X, const float* __restrict__ W,
    const float* __restrict__ Bv, float* __restrict__ Out,
    char* __restrict__ ws)
{
  const int tid  = threadIdx.x;
  const int wg   = blockIdx.x;      // 0..63 -> h cols [8wg, 8wg+8)
  const int lane = tid & 63;
  const int wv   = tid >> 6;        // 8 waves: m = wv>>1, n = wv&1
  const int m    = wv >> 1;
  const int n    = wv & 1;
  const int c16  = lane & 15;       // packed col = g*4 + q
  const int kgrp = lane >> 4;
  const int gg   = c16 >> 2;        // 0=f 1=i 2=g 3=o
  const int q    = c16 & 3;

  char* Xf   = ws;
  char* ring = ws + RING_OFF;

  // ---- zero both ring slots with sc0sc1 stores (visible to sc0sc1 pollers) ----
  {
    const int id = wg * 512 + tid;
    if (id < 16384) {
      u32x4 z = {0u, 0u, 0u, 0u};
      char* p = ring + (size_t)id * 16;
      asm volatile("global_store_dwordx4 %0, %1, off sc0 sc1" :: "v"(p), "v"(z) : "memory");
    }
  }

  // ---- one-time: X (fp32) -> Xf (bf16, A-frag-major) [round-5 verified] ----
  for (int id = wg * 512 + tid; id < 512 * 64 * 64; id += 64 * 512) {
    const int c8  = id & 63;
    const int row = (id >> 6) & 63;
    const int t   = id >> 12;
    const float* xp = X + ((size_t)(t * 64 + row)) * 512 + c8 * 8;
    const float4 a = *(const float4*)xp;
    const float4 b = *(const float4*)(xp + 4);
    short8 v;
    v[0]=f2bf(a.x); v[1]=f2bf(a.y); v[2]=f2bf(a.z); v[3]=f2bf(a.w);
    v[4]=f2bf(b.x); v[5]=f2bf(b.y); v[6]=f2bf(b.z); v[7]=f2bf(b.w);
    *(short8*)(Xf + (size_t)t * 65536 + (row >> 4) * 16384 + (c8 >> 2) * 1024
               + ((((c8 & 3) << 4) | (row & 15))) * 16) = v;
  }
  __threadfence();                                   // write back dirty L2 (Xf)
  cg::this_grid().sync();
  __builtin_amdgcn_fence(__ATOMIC_ACQUIRE, "agent"); // one-time inv of stale clean lines

  // ---- W -> 32 persistent B-fragments: k = kk*32 + kgrp*8 + j [round-5 verified] ----
  const int gcol = gg * 512 + wg * 8 + n * 4 + q;
  short8 B[32];
  #pragma unroll
  for (int kk = 0; kk < 32; ++kk) {
    short8 v;
    #pragma unroll
    for (int j = 0; j < 8; ++j)
      v[j] = f2bf(W[(size_t)(kk * 32 + kgrp * 8 + j) * 2048 + gcol]);
    B[kk] = v;
  }
  const float bias = Bv[gcol];

  float cst[4] = {0.f, 0.f, 0.f, 0.f};

  // consumer poll base: granule(row, cg) at slot + row*2048 + cg*16, cg = 8kk+2kgrp+u
  const int prow = m * 16 + c16;                      // A row (batch)
  char* hb0 = ring + (size_t)prow * 2048 + kgrp * 32; // + slot*131072 at use

  for (int t = 0; t < T_STEPS; ++t) {
    f32x4 ac0 = {0,0,0,0}, ac1 = {0,0,0,0}, ac2 = {0,0,0,0}, ac3 = {0,0,0,0};

    // -------- x-phase (cached loads from Xf; off the recurrence chain) --------
    {
      const char* xa = Xf + (size_t)t * 65536 + m * 16384 + lane * 16;
      #pragma unroll
      for (int f = 0; f < 16; f += 4) {
        const short8 a0 = *(const short8*)(xa + (size_t)f * 1024);
        const short8 a1 = *(const short8*)(xa + (size_t)f * 1024 + 1024);
        const short8 a2 = *(const short8*)(xa + (size_t)f * 1024 + 2048);
        const short8 a3 = *(const short8*)(xa + (size_t)f * 1024 + 3072);
        ac0 = __builtin_amdgcn_mfma_f32_16x16x32_bf16(a0, B[f],     ac0, 0, 0, 0);
        ac1 = __builtin_amdgcn_mfma_f32_16x16x32_bf16(a1, B[f + 1], ac1, 0, 0, 0);
        ac2 = __builtin_amdgcn_mfma_f32_16x16x32_bf16(a2, B[f + 2], ac2, 0, 0, 0);
        ac3 = __builtin_amdgcn_mfma_f32_16x16x32_bf16(a3, B[f + 3], ac3, 0, 0, 0);
      }
    }

    // -------- h-phase: poll tagged granules (equality), then MFMA --------
    if (t > 0) {
      const char* hb = hb0 + (size_t)((t - 1) & 1) * 131072;
      const unsigned tg = (unsigned)t;
      u32x4 ga0,ga1,ga2,ga3,ga4,ga5,ga6,ga7,ga8,ga9,ga10,ga11,ga12,ga13,ga14,ga15;
      u32x4 gb0,gb1,gb2,gb3,gb4,gb5,gb6,gb7,gb8,gb9,gb10,gb11,gb12,gb13,gb14,gb15;
      for (;;) {
        #define PL(i, o0, o1) \
          asm volatile("global_load_dwordx4 %0, %2, off offset:" #o0 " sc0 sc1\n\t" \
                       "global_load_dwordx4 %1, %2, off offset:" #o1 " sc0 sc1" \
                       : "=v"(ga##i), "=v"(gb##i) : "v"(hb))
        PL(0,0,16);       PL(1,128,144);    PL(2,256,272);    PL(3,384,400);
        PL(4,512,528);    PL(5,640,656);    PL(6,768,784);    PL(7,896,912);
        PL(8,1024,1040);  PL(9,1152,1168);  PL(10,1280,1296); PL(11,1408,1424);
        PL(12,1536,1552); PL(13,1664,1680); PL(14,1792,1808); PL(15,1920,1936);
        #undef PL
        asm volatile("s_waitcnt vmcnt(0)" ::: "memory");
        unsigned bad = 0;
        #define CK(i) bad |= (ga##i.x ^ tg) | (ga##i.z ^ tg) | (gb##i.x ^ tg) | (gb##i.z ^ tg)
        CK(0); CK(1); CK(2); CK(3); CK(4); CK(5); CK(6); CK(7);
        CK(8); CK(9); CK(10); CK(11); CK(12); CK(13); CK(14); CK(15);
        #undef CK
        if (!__any((int)(bad & 0xffffu))) break;
      }
      // extract bf16 (high halves) -> A frags, MFMA against B[16+kk]
      #define HF(i, ACC, BI) { \
        u32x4 dv; \
        dv.x = (ga##i.x >> 16) | (ga##i.y & 0xffff0000u); \
        dv.y = (ga##i.z >> 16) | (ga##i.w & 0xffff0000u); \
        dv.z = (gb##i.x >> 16) | (gb##i.y & 0xffff0000u); \
        dv.w = (gb##i.z >> 16) | (gb##i.w & 0xffff0000u); \
        ACC = __builtin_amdgcn_mfma_f32_16x16x32_bf16(as_s8(dv), B[BI], ACC, 0, 0, 0); }
      HF(0,  ac0, 16); HF(1,  ac1, 17); HF(2,  ac2, 18); HF(3,  ac3, 19);
      HF(4,  ac0, 20); HF(5,  ac1, 21); HF(6,  ac2, 22); HF(7,  ac3, 23);
      HF(8,  ac0, 24); HF(9,  ac1, 25); HF(10, ac2, 26); HF(11, ac3, 27);
      HF(12, ac0, 28); HF(13, ac1, 29); HF(14, ac2, 30); HF(15, ac3, 31);
      #undef HF
    }

    // -------- pointwise [round-5 verified layout, shfl 4/8/12] --------
    float hv[4], cnv[4];
    #pragma unroll
    for (int r = 0; r < 4; ++r) {
      const float pre = ac0[r] + ac1[r] + ac2[r] + ac3[r] + bias;
      const float e   = __expf((gg == 2) ? -2.f * pre : -pre);
      const float act = (gg == 2) ? (2.f / (1.f + e) - 1.f) : (1.f / (1.f + e));
      const float vi  = __shfl_xor(act, 4);     // f-lane <- i
      const float vg  = __shfl_xor(act, 8);     // f-lane <- g
      const float cn  = act * cst[r] + vi * vg; // valid on f-lanes
      if (gg == 0) cst[r] = cn;
      const float e2  = __expf(-2.f * cn);
      float tn = 2.f / (1.f + e2) - 1.f;
      tn = __shfl_xor(tn, 12);                  // o-lane <- tanh(c_new)
      hv[r]  = act * tn;                        // valid on o-lanes
      cnv[r] = cn;
    }

    // -------- publish h_t: tagged granules, fire-and-forget (no drain) --------
    {
      const unsigned tgp = (unsigned)(t + 1);
      char* rp = ring + (size_t)(t & 1) * 131072
               + (size_t)(m * 16 + kgrp * 4) * 2048 + (wg * 2 + n) * 16;
      #pragma unroll
      for (int r = 0; r < 4; ++r) {
        const unsigned w = (bfbits(hv[r]) << 16) | tgp;
        const unsigned x = (unsigned)__shfl_xor((int)w, 1);
        const unsigned y = (unsigned)__shfl_xor((int)w, 2);
        const unsigned z = (unsigned)__shfl_xor((int)x, 2);
        if (c16 == 12) {   // q==0 o-lane holds cols [q0,q1,q2,q3] for this row
          u32x4 gr; gr.x = w; gr.y = x; gr.z = y; gr.w = z;
          asm volatile("global_store_dwordx4 %0, %1, off sc0 sc1"
                       :: "v"(rp + (size_t)r * 2048), "v"(gr) : "memory");
        }
      }
    }

    // -------- Out stores (plain cached; off-chain) --------
    const int hc = wg * 8 + n * 4 + q;
    if (gg == 3) {
      float* op = Out + ((size_t)t * 64 + m * 16 + kgrp * 4) * 512 + hc;
      #pragma unroll
      for (int r = 0; r < 4; ++r) op[(size_t)r * 512] = hv[r];
      if (t == T_STEPS - 1) {
        #pragma unroll
        for (int r = 0; r < 4; ++r)
          Out[16777216u + (size_t)(m * 16 + kgrp * 4 + r) * 512 + hc] = hv[r];     // hx
      }
    }
    if (gg == 0 && t == T_STEPS - 1) {
      #pragma unroll
      for (int r = 0; r < 4; ++r)
        Out[16777216u + 32768u + (size_t)(m * 16 + kgrp * 4 + r) * 512 + hc] = cnv[r]; // cx
    }
  }
}

extern "C" void kernel_launch(void* const* d_in, const int* in_sizes, int n_in,
                              void* d_out, int out_size, void* d_ws, size_t ws_size,
                              hipStream_t stream) {
  if (ws_size < (size_t)WS_NEED) return;

  const float* X  = (const float*)d_in[0];
  const float* W  = (const float*)d_in[1];
  const float* Bv = (const float*)d_in[2];
  float* Out = (float*)d_out;
  char*  ws  = (char*)d_ws;

  void* args[5];
  args[0] = (void*)&X;
  args[1] = (void*)&W;
  args[2] = (void*)&Bv;
  args[3] = (void*)&Out;
  args[4] = (void*)&ws;
  hipLaunchCooperativeKernel((const void*)lstm_kernel, dim3(64), dim3(512),
                             args, 0, stream);
}

// Round 8
// 3189.040 us; speedup vs baseline: 3.7536x; 3.7536x over previous
//
#include <hip/hip_runtime.h>
#include <hip/hip_bf16.h>
#include <hip/hip_cooperative_groups.h>

namespace cg = cooperative_groups;

#define T_STEPS 512
// ws: Xf bf16 frag-major [0,32MiB) | ring 2x64KiB | flags 64x64B
#define RING_OFF 33554432u
#define FLAG_OFF 33685504u
#define WS_NEED  33689600u

typedef __attribute__((ext_vector_type(4))) float f32x4;
typedef __attribute__((ext_vector_type(8))) short short8;
typedef __attribute__((ext_vector_type(4))) unsigned int u32x4;

__device__ __forceinline__ short f2bf(float f) {
  __hip_bfloat16 h = __float2bfloat16(f);   // RNE
  return *reinterpret_cast<short*>(&h);
}
__device__ __forceinline__ unsigned bfbits(float f) {
  __hip_bfloat16 h = __float2bfloat16(f);
  return (unsigned)*reinterpret_cast<unsigned short*>(&h);
}
__device__ __forceinline__ short8 as_s8(u32x4 v) {
  union { u32x4 u; short8 s; } x; x.u = v; return x.s;
}

__global__ __launch_bounds__(512, 2) void lstm_kernel(
    const float* __restrict__ X, const float* __restrict__ W,
    const float* __restrict__ Bv, float* __restrict__ Out,
    char* __restrict__ ws)
{
  __shared__ char BxL[32768];       // x-half B-frags: [n 2][frag 16][lane 64]*16B

  const int tid  = threadIdx.x;
  const int wg   = blockIdx.x;      // 0..63 -> h cols [8wg, 8wg+8)
  const int lane = tid & 63;
  const int wv   = tid >> 6;        // 8 waves: m = wv>>1, n = wv&1
  const int m    = wv >> 1;
  const int n    = wv & 1;
  const int c16  = lane & 15;       // packed col = g*4 + q
  const int kgrp = lane >> 4;
  const int gg   = c16 >> 2;        // 0=f 1=i 2=g 3=o
  const int q    = c16 & 3;

  char*     Xf    = ws;
  char*     ring  = ws + RING_OFF;
  unsigned* flags = (unsigned*)(ws + FLAG_OFF);

  // ---- zero my flag (before grid sync; robust across graph replays) ----
  if (tid == 0)
    __hip_atomic_store(&flags[wg * 16], 0u, __ATOMIC_RELAXED, __HIP_MEMORY_SCOPE_AGENT);

  // ---- one-time: X (fp32) -> Xf (bf16, A-frag-major) [round-5 verified] ----
  for (int id = wg * 512 + tid; id < 512 * 64 * 64; id += 64 * 512) {
    const int c8  = id & 63;
    const int row = (id >> 6) & 63;
    const int t   = id >> 12;
    const float* xp = X + ((size_t)(t * 64 + row)) * 512 + c8 * 8;
    const float4 a = *(const float4*)xp;
    const float4 b = *(const float4*)(xp + 4);
    short8 v;
    v[0]=f2bf(a.x); v[1]=f2bf(a.y); v[2]=f2bf(a.z); v[3]=f2bf(a.w);
    v[4]=f2bf(b.x); v[5]=f2bf(b.y); v[6]=f2bf(b.z); v[7]=f2bf(b.w);
    *(short8*)(Xf + (size_t)t * 65536 + (row >> 4) * 16384 + (c8 >> 2) * 1024
               + ((((c8 & 3) << 4) | (row & 15))) * 16) = v;
  }
  __threadfence();                                   // write back dirty L2 (Xf)
  cg::this_grid().sync();
  __builtin_amdgcn_fence(__ATOMIC_ACQUIRE, "agent"); // one-time inv of stale clean lines

  // ---- W: h-half -> 16 register fragments; x-half -> LDS frags ----
  const int gcol = gg * 512 + wg * 8 + n * 4 + q;    // actual W column
  short8 Bh[16];
  #pragma unroll
  for (int kk = 0; kk < 16; ++kk) {
    short8 v;
    #pragma unroll
    for (int j = 0; j < 8; ++j)
      v[j] = f2bf(W[(size_t)(512 + kk * 32 + kgrp * 8 + j) * 2048 + gcol]);
    Bh[kk] = v;
  }
  if (wv < 2) {                     // waves (m=0,n=0/1) write region n=wv
    for (int f = 0; f < 16; ++f) {
      short8 v;
      #pragma unroll
      for (int j = 0; j < 8; ++j)
        v[j] = f2bf(W[(size_t)(f * 32 + kgrp * 8 + j) * 2048 + gcol]);
      *(short8*)(BxL + wv * 16384 + f * 1024 + lane * 16) = v;
    }
  }
  __syncthreads();
  const float bias = Bv[gcol];

  float cst[4] = {0.f, 0.f, 0.f, 0.f};

  // ---- x-prefetch registers; 4 asm blocks, EARLY-CLOBBER outputs (r7 crash fix) ----
  u32x4 x0,x1,x2,x3,x4,x5,x6,x7,x8,x9,x10,x11,x12,x13,x14,x15;
  #define PFX4(base, o0, o1, o2, o3) \
    asm volatile( \
      "global_load_dwordx4 %0, %4, off\n\t"             \
      "global_load_dwordx4 %1, %4, off offset:1024\n\t" \
      "global_load_dwordx4 %2, %4, off offset:2048\n\t" \
      "global_load_dwordx4 %3, %4, off offset:3072"     \
      : "=&v"(o0), "=&v"(o1), "=&v"(o2), "=&v"(o3) : "v"(base))
  #define PFX(tt) do { \
    const char* xb_ = Xf + (size_t)(tt) * 65536 + m * 16384 + lane * 16; \
    PFX4(xb_,          x0,  x1,  x2,  x3);  \
    PFX4(xb_ + 4096,   x4,  x5,  x6,  x7);  \
    PFX4(xb_ + 8192,   x8,  x9,  x10, x11); \
    PFX4(xb_ + 12288,  x12, x13, x14, x15); \
  } while (0)

  PFX(0);   // prologue

  for (int t = 0; t < T_STEPS; ++t) {
    // -------- consume prefetched x(t) (drained by end-of-prev-iter vmcnt(0)) --------
    asm volatile("s_waitcnt vmcnt(0)" ::: "memory");
    __builtin_amdgcn_sched_barrier(0);

    f32x4 ac0 = {0,0,0,0}, ac1 = {0,0,0,0}, ac2 = {0,0,0,0}, ac3 = {0,0,0,0};
    const char* bxp = BxL + n * 16384 + lane * 16;
    #define XM(i, ACC) ACC = __builtin_amdgcn_mfma_f32_16x16x32_bf16( \
        as_s8(x##i), *(const short8*)(bxp + i * 1024), ACC, 0, 0, 0)
    XM(0,ac0);  XM(1,ac1);  XM(2,ac2);  XM(3,ac3);
    XM(4,ac0);  XM(5,ac1);  XM(6,ac2);  XM(7,ac3);
    XM(8,ac0);  XM(9,ac1);  XM(10,ac2); XM(11,ac3);
    XM(12,ac0); XM(13,ac1); XM(14,ac2); XM(15,ac3);
    #undef XM

    if (t > 0) {
      // ---- poll (wave 0 only; round-1/5-verified protocol) ----
      if (wv == 0) {
        while (__hip_atomic_load(&flags[lane * 16], __ATOMIC_RELAXED,
                                 __HIP_MEMORY_SCOPE_AGENT) < (unsigned)t) {}
      }
      __builtin_amdgcn_s_barrier();      // raw: ordering via LLC-bypass loads below
      __builtin_amdgcn_sched_barrier(0); // pin h-loads after the barrier

      // ---- h-loads first, then x(t+1) prefetch: vmcnt(16) waits h only ----
      const char* hp0 = ring + (size_t)((t - 1) & 1) * 65536 + m * 16384 + lane * 16;
      const char* hp1 = hp0 + 4096;
      const char* hp2 = hp0 + 8192;
      const char* hp3 = hp0 + 12288;
      u32x4 h0,h1,h2,h3,h4,h5,h6,h7,h8,h9,h10,h11,h12,h13,h14,h15;
      #define LDR(base, off, vv) \
        asm volatile("global_load_dwordx4 %0, %1, off offset:" off " sc0 sc1" \
                     : "=&v"(vv) : "v"(base))
      LDR(hp0, "0", h0);  LDR(hp0, "1024", h1);  LDR(hp0, "2048", h2);  LDR(hp0, "3072", h3);
      LDR(hp1, "0", h4);  LDR(hp1, "1024", h5);  LDR(hp1, "2048", h6);  LDR(hp1, "3072", h7);
      LDR(hp2, "0", h8);  LDR(hp2, "1024", h9);  LDR(hp2, "2048", h10); LDR(hp2, "3072", h11);
      LDR(hp3, "0", h12); LDR(hp3, "1024", h13); LDR(hp3, "2048", h14); LDR(hp3, "3072", h15);
      #undef LDR
      PFX(t == T_STEPS - 1 ? t : t + 1);

      asm volatile("s_waitcnt vmcnt(16)" ::: "memory");   // oldest 16 = the h-loads
      __builtin_amdgcn_sched_barrier(0);                  // rule #18: pin MFMAs after wait
      #define HM(i, ACC) ACC = __builtin_amdgcn_mfma_f32_16x16x32_bf16( \
          as_s8(h##i), Bh[i], ACC, 0, 0, 0)
      HM(0,ac0);  HM(1,ac1);  HM(2,ac2);  HM(3,ac3);
      HM(4,ac0);  HM(5,ac1);  HM(6,ac2);  HM(7,ac3);
      HM(8,ac0);  HM(9,ac1);  HM(10,ac2); HM(11,ac3);
      HM(12,ac0); HM(13,ac1); HM(14,ac2); HM(15,ac3);
      #undef HM
    } else {
      PFX(1);
    }

    // -------- pointwise [round-5 verified layout, shfl 4/8/12] --------
    float hv[4], cnv[4];
    #pragma unroll
    for (int r = 0; r < 4; ++r) {
      const float pre = ac0[r] + ac1[r] + ac2[r] + ac3[r] + bias;
      const float e   = __expf((gg == 2) ? -2.f * pre : -pre);
      const float act = (gg == 2) ? (2.f / (1.f + e) - 1.f) : (1.f / (1.f + e));
      const float vi  = __shfl_xor(act, 4);     // f-lane <- i
      const float vg  = __shfl_xor(act, 8);     // f-lane <- g
      const float cn  = act * cst[r] + vi * vg; // valid on f-lanes
      if (gg == 0) cst[r] = cn;
      const float e2  = __expf(-2.f * cn);
      float tn = 2.f / (1.f + e2) - 1.f;
      tn = __shfl_xor(tn, 12);                  // o-lane <- tanh(c_new)
      hv[r]  = act * tn;                        // valid on o-lanes
      cnv[r] = cn;
    }

    // -------- ring publish [round-5 verified packing] --------
    {
      char* rp = ring + (size_t)(t & 1) * 65536 + m * 16384 + (wg >> 2) * 1024
               + (((wg & 3) << 4) + kgrp * 4) * 16 + (n * 4 + q) * 2;
      #pragma unroll
      for (int r = 0; r < 4; ++r) {
        const unsigned hb = bfbits(hv[r]);
        const unsigned pb = (unsigned)__shfl_xor((int)hb, 1);  // partner col
        if (gg == 3 && !(q & 1))
          __hip_atomic_store((unsigned*)(rp + r * 16),
                             (hb & 0xffffu) | (pb << 16),
                             __ATOMIC_RELAXED, __HIP_MEMORY_SCOPE_AGENT);
      }
    }

    // -------- drain ring stores, barrier, publish flag, THEN Out stores --------
    asm volatile("s_waitcnt vmcnt(0)" ::: "memory");
    __builtin_amdgcn_sched_barrier(0);
    __builtin_amdgcn_s_barrier();
    if (tid == 0)
      __hip_atomic_store(&flags[wg * 16], (unsigned)(t + 1),
                         __ATOMIC_RELEASE, __HIP_MEMORY_SCOPE_AGENT);

    const int hc = wg * 8 + n * 4 + q;
    if (gg == 3) {
      float* op = Out + ((size_t)t * 64 + m * 16 + kgrp * 4) * 512 + hc;
      #pragma unroll
      for (int r = 0; r < 4; ++r) op[(size_t)r * 512] = hv[r];
      if (t == T_STEPS - 1) {
        #pragma unroll
        for (int r = 0; r < 4; ++r)
          Out[16777216u + (size_t)(m * 16 + kgrp * 4 + r) * 512 + hc] = hv[r];     // hx
      }
    }
    if (gg == 0 && t == T_STEPS - 1) {
      #pragma unroll
      for (int r = 0; r < 4; ++r)
        Out[16777216u + 32768u + (size_t)(m * 16 + kgrp * 4 + r) * 512 + hc] = cnv[r]; // cx
    }
  }
  #undef PFX
  #undef PFX4
}

extern "C" void kernel_launch(void* const* d_in, const int* in_sizes, int n_in,
                              void* d_out, int out_size, void* d_ws, size_t ws_size,
                              hipStream_t stream) {
  if (ws_size < (size_t)WS_NEED) return;

  const float* X  = (const float*)d_in[0];
  const float* W  = (const float*)d_in[1];
  const float* Bv = (const float*)d_in[2];
  float* Out = (float*)d_out;
  char*  ws  = (char*)d_ws;

  void* args[5];
  args[0] = (void*)&X;
  args[1] = (void*)&W;
  args[2] = (void*)&Bv;
  args[3] = (void*)&Out;
  args[4] = (void*)&ws;
  hipLaunchCooperativeKernel((const void*)lstm_kernel, dim3(64), dim3(512),
                             args, 0, stream);
}

// Round 9
// 2382.277 us; speedup vs baseline: 5.0248x; 1.3387x over previous
//
#include <hip/hip_runtime.h>
#include <hip/hip_bf16.h>
#include <hip/hip_cooperative_groups.h>

namespace cg = cooperative_groups;

#define T_STEPS 512
// ws: Xf bf16 frag-major [0,32MiB) | ring 2x64KiB | flags 64x64B
#define RING_OFF 33554432u
#define FLAG_OFF 33685504u
#define WS_NEED  33689600u

typedef __attribute__((ext_vector_type(4))) float f32x4;
typedef __attribute__((ext_vector_type(8))) short short8;
typedef __attribute__((ext_vector_type(4))) unsigned int u32x4;

__device__ __forceinline__ short f2bf(float f) {
  __hip_bfloat16 h = __float2bfloat16(f);   // RNE
  return *reinterpret_cast<short*>(&h);
}
__device__ __forceinline__ unsigned bfbits(float f) {
  __hip_bfloat16 h = __float2bfloat16(f);
  return (unsigned)*reinterpret_cast<unsigned short*>(&h);
}
__device__ __forceinline__ short8 as_s8(u32x4 v) {
  union { u32x4 u; short8 s; } x; x.u = v; return x.s;
}

__global__ __launch_bounds__(512, 2) void lstm_kernel(
    const float* __restrict__ X, const float* __restrict__ W,
    const float* __restrict__ Bv, float* __restrict__ Out,
    char* __restrict__ ws)
{
  __shared__ char BxL[32768];       // x-half B-frags: [n 2][frag 16][lane 64]*16B

  const int tid  = threadIdx.x;
  const int wg   = blockIdx.x;      // 0..63 -> h cols [8wg, 8wg+8)
  const int lane = tid & 63;
  const int wv   = tid >> 6;        // 8 waves: m = wv>>1, n = wv&1
  const int m    = wv >> 1;
  const int n    = wv & 1;
  const int c16  = lane & 15;       // packed col = g*4 + q
  const int kgrp = lane >> 4;
  const int gg   = c16 >> 2;        // 0=f 1=i 2=g 3=o
  const int q    = c16 & 3;

  char*     Xf    = ws;
  char*     ring  = ws + RING_OFF;
  unsigned* flags = (unsigned*)(ws + FLAG_OFF);

  // ---- zero my flag (before grid sync; robust across graph replays) ----
  if (tid == 0)
    __hip_atomic_store(&flags[wg * 16], 0u, __ATOMIC_RELAXED, __HIP_MEMORY_SCOPE_AGENT);

  // ---- one-time: X (fp32) -> Xf (bf16, A-frag-major) [round-5 verified] ----
  for (int id = wg * 512 + tid; id < 512 * 64 * 64; id += 64 * 512) {
    const int c8  = id & 63;
    const int row = (id >> 6) & 63;
    const int t   = id >> 12;
    const float* xp = X + ((size_t)(t * 64 + row)) * 512 + c8 * 8;
    const float4 a = *(const float4*)xp;
    const float4 b = *(const float4*)(xp + 4);
    short8 v;
    v[0]=f2bf(a.x); v[1]=f2bf(a.y); v[2]=f2bf(a.z); v[3]=f2bf(a.w);
    v[4]=f2bf(b.x); v[5]=f2bf(b.y); v[6]=f2bf(b.z); v[7]=f2bf(b.w);
    *(short8*)(Xf + (size_t)t * 65536 + (row >> 4) * 16384 + (c8 >> 2) * 1024
               + ((((c8 & 3) << 4) | (row & 15))) * 16) = v;
  }
  __threadfence();                                   // write back dirty L2 (Xf)
  cg::this_grid().sync();
  __builtin_amdgcn_fence(__ATOMIC_ACQUIRE, "agent"); // one-time inv of stale clean lines

  // ---- W: h-half -> 16 register fragments; x-half -> LDS frags ----
  const int gcol = gg * 512 + wg * 8 + n * 4 + q;    // actual W column
  short8 Bh[16];
  #pragma unroll
  for (int kk = 0; kk < 16; ++kk) {
    short8 v;
    #pragma unroll
    for (int j = 0; j < 8; ++j)
      v[j] = f2bf(W[(size_t)(512 + kk * 32 + kgrp * 8 + j) * 2048 + gcol]);
    Bh[kk] = v;
  }
  if (wv < 2) {                     // waves (m=0,n=0/1) write region n=wv
    for (int f = 0; f < 16; ++f) {
      short8 v;
      #pragma unroll
      for (int j = 0; j < 8; ++j)
        v[j] = f2bf(W[(size_t)(f * 32 + kgrp * 8 + j) * 2048 + gcol]);
      *(short8*)(BxL + wv * 16384 + f * 1024 + lane * 16) = v;
    }
  }
  __syncthreads();
  const float bias = Bv[gcol];

  float cst[4] = {0.f, 0.f, 0.f, 0.f};

  // ---- x-prefetch registers; 4 asm blocks, EARLY-CLOBBER outputs ----
  u32x4 x0,x1,x2,x3,x4,x5,x6,x7,x8,x9,x10,x11,x12,x13,x14,x15;
  #define PFX4(base, o0, o1, o2, o3) \
    asm volatile( \
      "global_load_dwordx4 %0, %4, off\n\t"             \
      "global_load_dwordx4 %1, %4, off offset:1024\n\t" \
      "global_load_dwordx4 %2, %4, off offset:2048\n\t" \
      "global_load_dwordx4 %3, %4, off offset:3072"     \
      : "=&v"(o0), "=&v"(o1), "=&v"(o2), "=&v"(o3) : "v"(base))
  #define PFX(tt) do { \
    const char* xb_ = Xf + (size_t)(tt) * 65536 + m * 16384 + lane * 16; \
    PFX4(xb_,          x0,  x1,  x2,  x3);  \
    PFX4(xb_ + 4096,   x4,  x5,  x6,  x7);  \
    PFX4(xb_ + 8192,   x8,  x9,  x10, x11); \
    PFX4(xb_ + 12288,  x12, x13, x14, x15); \
  } while (0)

  PFX(0);   // prologue

  for (int t = 0; t < T_STEPS; ++t) {
    // -------- consume prefetched x(t) --------
    asm volatile("s_waitcnt vmcnt(0)" ::: "memory");
    __builtin_amdgcn_sched_barrier(0);

    f32x4 ac0 = {0,0,0,0}, ac1 = {0,0,0,0}, ac2 = {0,0,0,0}, ac3 = {0,0,0,0};
    const char* bxp = BxL + n * 16384 + lane * 16;
    #define XM(i, ACC) ACC = __builtin_amdgcn_mfma_f32_16x16x32_bf16( \
        as_s8(x##i), *(const short8*)(bxp + i * 1024), ACC, 0, 0, 0)
    XM(0,ac0);  XM(1,ac1);  XM(2,ac2);  XM(3,ac3);
    XM(4,ac0);  XM(5,ac1);  XM(6,ac2);  XM(7,ac3);
    XM(8,ac0);  XM(9,ac1);  XM(10,ac2); XM(11,ac3);
    XM(12,ac0); XM(13,ac1); XM(14,ac2); XM(15,ac3);
    #undef XM

    if (t > 0) {
      // ---- poll (wave 0 only; verified protocol) ----
      if (wv == 0) {
        while (__hip_atomic_load(&flags[lane * 16], __ATOMIC_RELAXED,
                                 __HIP_MEMORY_SCOPE_AGENT) < (unsigned)t) {}
      }
      __builtin_amdgcn_s_barrier();      // raw: ordering via LLC-bypass loads below
      __builtin_amdgcn_sched_barrier(0); // pin h-loads after the barrier

      // ---- h-loads first, then x(t+1) prefetch: vmcnt(16) waits h only ----
      const char* hp0 = ring + (size_t)((t - 1) & 1) * 65536 + m * 16384 + lane * 16;
      const char* hp1 = hp0 + 4096;
      const char* hp2 = hp0 + 8192;
      const char* hp3 = hp0 + 12288;
      u32x4 h0,h1,h2,h3,h4,h5,h6,h7,h8,h9,h10,h11,h12,h13,h14,h15;
      #define LDR(base, off, vv) \
        asm volatile("global_load_dwordx4 %0, %1, off offset:" off " sc0 sc1" \
                     : "=&v"(vv) : "v"(base))
      LDR(hp0, "0", h0);  LDR(hp0, "1024", h1);  LDR(hp0, "2048", h2);  LDR(hp0, "3072", h3);
      LDR(hp1, "0", h4);  LDR(hp1, "1024", h5);  LDR(hp1, "2048", h6);  LDR(hp1, "3072", h7);
      LDR(hp2, "0", h8);  LDR(hp2, "1024", h9);  LDR(hp2, "2048", h10); LDR(hp2, "3072", h11);
      LDR(hp3, "0", h12); LDR(hp3, "1024", h13); LDR(hp3, "2048", h14); LDR(hp3, "3072", h15);
      #undef LDR
      PFX(t == T_STEPS - 1 ? t : t + 1);

      asm volatile("s_waitcnt vmcnt(16)" ::: "memory");   // oldest 16 = the h-loads
      __builtin_amdgcn_sched_barrier(0);                  // rule #18
      #define HM(i, ACC) ACC = __builtin_amdgcn_mfma_f32_16x16x32_bf16( \
          as_s8(h##i), Bh[i], ACC, 0, 0, 0)
      HM(0,ac0);  HM(1,ac1);  HM(2,ac2);  HM(3,ac3);
      HM(4,ac0);  HM(5,ac1);  HM(6,ac2);  HM(7,ac3);
      HM(8,ac0);  HM(9,ac1);  HM(10,ac2); HM(11,ac3);
      HM(12,ac0); HM(13,ac1); HM(14,ac2); HM(15,ac3);
      #undef HM
    } else {
      PFX(1);
    }

    // -------- pointwise [verified layout, shfl 4/8/12] --------
    float hv[4], cnv[4];
    #pragma unroll
    for (int r = 0; r < 4; ++r) {
      const float pre = ac0[r] + ac1[r] + ac2[r] + ac3[r] + bias;
      const float e   = __expf((gg == 2) ? -2.f * pre : -pre);
      const float act = (gg == 2) ? (2.f / (1.f + e) - 1.f) : (1.f / (1.f + e));
      const float vi  = __shfl_xor(act, 4);     // f-lane <- i
      const float vg  = __shfl_xor(act, 8);     // f-lane <- g
      const float cn  = act * cst[r] + vi * vg; // valid on f-lanes
      if (gg == 0) cst[r] = cn;
      const float e2  = __expf(-2.f * cn);
      float tn = 2.f / (1.f + e2) - 1.f;
      tn = __shfl_xor(tn, 12);                  // o-lane <- tanh(c_new)
      hv[r]  = act * tn;                        // valid on o-lanes
      cnv[r] = cn;
    }

    // -------- ring publish [verified packing; sc0sc1 direct to LLC] --------
    {
      char* rp = ring + (size_t)(t & 1) * 65536 + m * 16384 + (wg >> 2) * 1024
               + (((wg & 3) << 4) + kgrp * 4) * 16 + (n * 4 + q) * 2;
      #pragma unroll
      for (int r = 0; r < 4; ++r) {
        const unsigned hb = bfbits(hv[r]);
        const unsigned pb = (unsigned)__shfl_xor((int)hb, 1);  // partner col
        if (gg == 3 && !(q & 1))
          __hip_atomic_store((unsigned*)(rp + r * 16),
                             (hb & 0xffffu) | (pb << 16),
                             __ATOMIC_RELAXED, __HIP_MEMORY_SCOPE_AGENT);
      }
    }

    // -------- drain ring stores, barrier, RELAXED flag publish (r9 change) --------
    asm volatile("s_waitcnt vmcnt(0)" ::: "memory");
    __builtin_amdgcn_sched_barrier(0);
    __builtin_amdgcn_s_barrier();
    if (tid == 0) {
      // Round-9 single change: relaxed raw store instead of __ATOMIC_RELEASE.
      // Ordering is provided by the vmcnt(0) drain above: ring data is already
      // at the LLC (coherence point for sc0sc1) when this store issues.
      unsigned tv = (unsigned)(t + 1);
      unsigned* fp = &flags[wg * 16];
      asm volatile("global_store_dword %0, %1, off sc0 sc1"
                   :: "v"(fp), "v"(tv) : "memory");
    }

    const int hc = wg * 8 + n * 4 + q;
    if (gg == 3) {
      float* op = Out + ((size_t)t * 64 + m * 16 + kgrp * 4) * 512 + hc;
      #pragma unroll
      for (int r = 0; r < 4; ++r) op[(size_t)r * 512] = hv[r];
      if (t == T_STEPS - 1) {
        #pragma unroll
        for (int r = 0; r < 4; ++r)
          Out[16777216u + (size_t)(m * 16 + kgrp * 4 + r) * 512 + hc] = hv[r];     // hx
      }
    }
    if (gg == 0 && t == T_STEPS - 1) {
      #pragma unroll
      for (int r = 0; r < 4; ++r)
        Out[16777216u + 32768u + (size_t)(m * 16 + kgrp * 4 + r) * 512 + hc] = cnv[r]; // cx
    }
  }
  #undef PFX
  #undef PFX4
}

extern "C" void kernel_launch(void* const* d_in, const int* in_sizes, int n_in,
                              void* d_out, int out_size, void* d_ws, size_t ws_size,
                              hipStream_t stream) {
  if (ws_size < (size_t)WS_NEED) return;

  const float* X  = (const float*)d_in[0];
  const float* W  = (const float*)d_in[1];
  const float* Bv = (const float*)d_in[2];
  float* Out = (float*)d_out;
  char*  ws  = (char*)d_ws;

  void* args[5];
  args[0] = (void*)&X;
  args[1] = (void*)&W;
  args[2] = (void*)&Bv;
  args[3] = (void*)&Out;
  args[4] = (void*)&ws;
  hipLaunchCooperativeKernel((const void*)lstm_kernel, dim3(64), dim3(512),
                             args, 0, stream);
}